// Round 5
// baseline (205.807 us; speedup 1.0000x reference)
//
#include <hip/hip_runtime.h>

#define NN 8192
#define FIN 512
#define FOUT 256
#define JS 8
#define STRIP 1024   // j per wave strip
#define NSTEP 32     // 32 j per step

typedef _Float16 f16;
typedef __attribute__((ext_vector_type(8))) _Float16 f16x8;
typedef __attribute__((ext_vector_type(4))) _Float16 f16x4;
typedef __attribute__((ext_vector_type(4))) float f32x4;
typedef __attribute__((ext_vector_type(16))) float f32x16;
typedef __attribute__((ext_vector_type(4))) int i32x4;

__device__ __forceinline__ float lrelu(float x) { return fmaxf(x, 0.2f * x); }

// ---- prep W: f32 [FIN][FOUT] -> f16 hi/lo transposed [FOUT][FIN]
__global__ void k_prep_w(const float* __restrict__ W, f16* __restrict__ wth,
                         f16* __restrict__ wtl) {
  int id = blockIdx.x * 256 + threadIdx.x;
  int c = id >> 9, k = id & 511;
  float v = W[k * FOUT + c];
  f16 a = (f16)v;
  wth[c * FIN + k] = a;
  wtl[c * FIN + k] = (f16)(v - (float)a);
}

// ---- GEMM1: Wh = h @ W via split-f16 MFMA; h converted to hi/lo in-reg.
// Emits whT16 (f16, tiled [j/16][256 c][16 j]), Wh1, Wh2 (f32).
__launch_bounds__(256, 2)
__global__ void k_gemm1(const float* __restrict__ h, const f16* __restrict__ wth,
                        const f16* __restrict__ wtl, const float* __restrict__ avec,
                        f16* __restrict__ whT16, float* __restrict__ wh1,
                        float* __restrict__ wh2) {
  int i0 = blockIdx.x * 32;
  int tid = threadIdx.x;
  int w = tid >> 6, l = tid & 63, m = l & 15, g = l >> 4;
  f32x4 acc[2][4] = {};
#pragma unroll 1
  for (int k0 = 0; k0 < FIN; k0 += 32) {
    f16x8 ah[2], al[2], bh[4], bl[4];
#pragma unroll
    for (int rf = 0; rf < 2; ++rf) {
      int ro = (i0 + 16 * rf + m) * FIN + k0 + 8 * g;
      f32x4 va = *(const f32x4*)(h + ro);
      f32x4 vb = *(const f32x4*)(h + ro + 4);
#pragma unroll
      for (int e = 0; e < 4; ++e) {
        f16 x = (f16)va[e];
        ah[rf][e] = x;
        al[rf][e] = (f16)(va[e] - (float)x);
        f16 y = (f16)vb[e];
        ah[rf][4 + e] = y;
        al[rf][4 + e] = (f16)(vb[e] - (float)y);
      }
    }
#pragma unroll
    for (int cf = 0; cf < 4; ++cf) {
      int co = (64 * w + 16 * cf + m) * FIN + k0 + 8 * g;
      bh[cf] = *(const f16x8*)(wth + co);
      bl[cf] = *(const f16x8*)(wtl + co);
    }
#pragma unroll
    for (int rf = 0; rf < 2; ++rf)
#pragma unroll
      for (int cf = 0; cf < 4; ++cf) {
        acc[rf][cf] = __builtin_amdgcn_mfma_f32_16x16x32_f16(ah[rf], bh[cf], acc[rf][cf], 0, 0, 0);
        acc[rf][cf] = __builtin_amdgcn_mfma_f32_16x16x32_f16(ah[rf], bl[cf], acc[rf][cf], 0, 0, 0);
        acc[rf][cf] = __builtin_amdgcn_mfma_f32_16x16x32_f16(al[rf], bh[cf], acc[rf][cf], 0, 0, 0);
      }
  }
  __shared__ float tile[32][FOUT + 1];
#pragma unroll
  for (int rf = 0; rf < 2; ++rf)
#pragma unroll
    for (int cf = 0; cf < 4; ++cf)
#pragma unroll
      for (int r = 0; r < 4; ++r)
        tile[16 * rf + 4 * g + r][64 * w + 16 * cf + m] = acc[rf][cf][r];
  __syncthreads();
  {  // whT16 tiled write: thread = column c, 32 rows = 2 j16-groups
    int c = tid;
    f16x8 vv[4];
#pragma unroll
    for (int r = 0; r < 32; ++r) vv[r >> 3][r & 7] = (f16)tile[r][c];
    size_t base = ((size_t)(i0 >> 4) * 256 + c) * 16;
    *(f16x8*)(whT16 + base) = vv[0];
    *(f16x8*)(whT16 + base + 8) = vv[1];
    *(f16x8*)(whT16 + base + 4096) = vv[2];
    *(f16x8*)(whT16 + base + 4096 + 8) = vv[3];
  }
  {  // Wh1/Wh2 row dots: 8 lanes per row
    int r = tid >> 3, ls = tid & 7;
    float s1 = 0.f, s2 = 0.f;
    for (int c = ls; c < FOUT; c += 8) {
      float v = tile[r][c];
      s1 = fmaf(v, avec[c], s1);
      s2 = fmaf(v, avec[FOUT + c], s2);
    }
#pragma unroll
    for (int off = 1; off < 8; off <<= 1) {
      s1 += __shfl_xor(s1, off);
      s2 += __shfl_xor(s2, off);
    }
    if (ls == 0) {
      wh1[i0 + r] = s1;
      wh2[i0 + r] = s2;
    }
  }
}

// ---- global max of Wh2 (safe softmax shift bound)
__global__ void k_max2(const float* __restrict__ wh2, float* __restrict__ m2) {
  int t = threadIdx.x;
  float mx = -1e30f;
  for (int i = t; i < NN; i += 256) mx = fmaxf(mx, wh2[i]);
#pragma unroll
  for (int off = 1; off < 64; off <<= 1) mx = fmaxf(mx, __shfl_xor(mx, off));
  __shared__ float sm[4];
  if ((t & 63) == 0) sm[t >> 6] = mx;
  __syncthreads();
  if (t == 0) m2[0] = fmaxf(fmaxf(sm[0], sm[1]), fmaxf(sm[2], sm[3]));
}

// ---- fused masked-softmax + PV: barrier-FREE. 4 independent waves/block;
// wave = 32 rows x 1024-j strip x 256 cols. adj loaded coalesced (8x128B
// dense segments/instr), transposed via wave-private 4KB LDS tile
// (XOR-swizzled 16B granules); DS in-order per wave => no __syncthreads,
// so the depth-2 adj prefetch is never vmcnt(0)-drained.
__launch_bounds__(256, 2)
__global__ void k_attn(const int* __restrict__ adj, const f16* __restrict__ whT16,
                       const float* __restrict__ wh1, const float* __restrict__ wh2,
                       const float* __restrict__ m2g, f16* __restrict__ accP,
                       float* __restrict__ zP) {
  int bx = blockIdx.x;
  int js = bx & (JS - 1), rb = bx >> 3;
  int jbase = js * STRIP;
  int tid = threadIdx.x, w = tid >> 6, l = tid & 63;
  int lr = l & 31, hi = l >> 5;
  int i0w = rb * 128 + w * 32;

  __shared__ int adjT[4][32 * 32];  // wave-private [32 rows][8 granules x 4]
  int* aW = adjT[w];

  float M2 = m2g[0];
  float w1 = wh1[i0w + lr];
  float mrow = lrelu(w1 + M2);

  // coalesced load identity: lane covers (row 8q + (l>>3), granule l&7)
  int ldr = l >> 3, ldc = l & 7;
  const int* aSrc = adj + (size_t)(i0w + ldr) * NN + jbase + ldc * 4;
  int wbase = ldr * 32 + (ldc ^ ldr) * 4;  // swizzled write (r&7 == ldr)

  // transposed read: row lr, granules {2hi,2hi+1,2hi+4,2hi+5} ^ (lr&7)
  int rq[4];
#pragma unroll
  for (int qi = 0; qi < 4; ++qi) {
    int q = 2 * hi + 4 * (qi >> 1) + (qi & 1);
    rq[qi] = lr * 32 + (q ^ (lr & 7)) * 4;
  }

  f32x16 acc[8] = {};
  float zacc = 0.f;

  i32x4 R[2][4];
#pragma unroll
  for (int q = 0; q < 4; ++q)
    R[0][q] = __builtin_nontemporal_load((const i32x4*)(aSrc + (size_t)8 * q * NN));
#pragma unroll
  for (int q = 0; q < 4; ++q)
    R[1][q] = __builtin_nontemporal_load((const i32x4*)(aSrc + (size_t)8 * q * NN + 32));
#pragma unroll
  for (int q = 0; q < 4; ++q)
    *(i32x4*)(aW + wbase + q * 256) = R[0][q];  // stage adj(0)
#pragma unroll
  for (int q = 0; q < 4; ++q)
    R[0][q] = __builtin_nontemporal_load((const i32x4*)(aSrc + (size_t)8 * q * NN + 64));

  const size_t jb16 = (size_t)(jbase >> 4) * 256 * 16;
  const f16* bPB = whT16 + jb16 + (size_t)lr * 16 + hi * 8;
  const float* w2b = wh2 + jbase + 8 * hi;

#pragma unroll 1
  for (int t = 0; t < NSTEP; ++t) {
    int jc = t * 32;
    // A-source ints for step t (written last step)
    i32x4 av[4];
#pragma unroll
    for (int qi = 0; qi < 4; ++qi) av[qi] = *(const i32x4*)(aW + rq[qi]);
    // stage adj(t+1) (DS in-order: writes can't pass the reads above)
    int p = (t + 1) & 1;
#pragma unroll
    for (int q = 0; q < 4; ++q) *(i32x4*)(aW + wbase + q * 256) = R[p][q];
    // issue adj(t+3) into the freed reg buffer (~2 steps of latency cover)
    int tl = (t + 3 < NSTEP) ? t + 3 : NSTEP - 1;
#pragma unroll
    for (int q = 0; q < 4; ++q)
      R[p][q] = __builtin_nontemporal_load(
          (const i32x4*)(aSrc + (size_t)8 * q * NN + 32 * tl));
    // w2 (L1-resident strip, broadcast across lanes)
    f32x4 wv[4];
#pragma unroll
    for (int qi = 0; qi < 4; ++qi)
      wv[qi] = *(const f32x4*)(w2b + jc + 16 * (qi >> 1) + 4 * (qi & 1));
    // genP: pa[kb][e'] = P[row=lr][jc + 16*kb + 8*hi + e']
    f16x8 pa[2];
#pragma unroll
    for (int qi = 0; qi < 4; ++qi)
#pragma unroll
      for (int e = 0; e < 4; ++e) {
        float s = w1 + wv[qi][e];
        float sc = fmaxf(s, 0.2f * s);
        float pv = (av[qi][e] > 0) ? __expf(sc - mrow) : 0.f;
        zacc += pv;
        pa[qi >> 1][(qi & 1) * 4 + e] = (f16)pv;
      }
    // MFMA: B kb-granular to cap VGPR pressure
#pragma unroll
    for (int kb = 0; kb < 2; ++kb) {
      const f16* bk = bPB + ((size_t)(2 * t + kb) * 256) * 16;
#pragma unroll
      for (int half = 0; half < 2; ++half) {
        f16x8 bf[4];
#pragma unroll
        for (int c = 0; c < 4; ++c)
          bf[c] = *(const f16x8*)(bk + (size_t)(half * 4 + c) * 32 * 16);
#pragma unroll
        for (int c = 0; c < 4; ++c)
          acc[half * 4 + c] = __builtin_amdgcn_mfma_f32_32x32x16_f16(
              pa[kb], bf[c], acc[half * 4 + c], 0, 0, 0);
      }
    }
  }

  // Z: hi=0/1 lanes hold complementary j-halves of row lr
  zacc += __shfl_xor(zacc, 32);
  if (hi == 0) zP[(size_t)js * NN + i0w + lr] = zacc;

  // partial accumulator out, f16. C/D: col=lane&31, row=(r&3)+8*(r>>2)+4*hi
  f16* ap = accP + (size_t)js * NN * FOUT;
#pragma unroll
  for (int cf = 0; cf < 8; ++cf)
#pragma unroll
    for (int r = 0; r < 16; ++r) {
      int grow = i0w + (r & 3) + 8 * (r >> 2) + 4 * hi;
      int gcol = cf * 32 + lr;
      __builtin_nontemporal_store((f16)acc[cf][r], ap + (size_t)grow * FOUT + gcol);
    }
}

// ---- combine JS f16 partials, divide by Z, elu
__global__ void k_combine(const f16* __restrict__ accP, const float* __restrict__ zP,
                          float* __restrict__ out) {
  int id = blockIdx.x * 256 + threadIdx.x;
  size_t idx = (size_t)id * 4;
  int row = (int)(idx >> 8);
  f32x4 s = {};
#pragma unroll
  for (int p = 0; p < JS; ++p) {
    f16x4 v = *(const f16x4*)(accP + (size_t)p * NN * FOUT + idx);
#pragma unroll
    for (int i = 0; i < 4; ++i) s[i] += (float)v[i];
  }
  float z = 0.f;
#pragma unroll
  for (int p = 0; p < JS; ++p) z += zP[(size_t)p * NN + row];
  float inv = (z > 0.f) ? 1.f / z : 0.f;
  f32x4 o;
#pragma unroll
  for (int i = 0; i < 4; ++i) {
    float x = s[i] * inv;
    o[i] = (x > 0.f) ? x : expm1f(x);
  }
  *(f32x4*)(out + idx) = o;
}

extern "C" void kernel_launch(void* const* d_in, const int* in_sizes, int n_in,
                              void* d_out, int out_size, void* d_ws, size_t ws_size,
                              hipStream_t stream) {
  const float* h = (const float*)d_in[0];
  const int* adj = (const int*)d_in[1];
  const float* W = (const float*)d_in[2];
  const float* a = (const float*)d_in[3];
  (void)in_sizes; (void)n_in; (void)out_size; (void)ws_size;

  char* ws = (char*)d_ws;
  size_t off = 0;
  auto alloc = [&](size_t bytes) {
    void* p = ws + off;
    off = (off + bytes + 255) & ~(size_t)255;
    return p;
  };
  f16* accP = (f16*)alloc((size_t)JS * NN * FOUT * 2);  // 32 MB
  f16* whT16 = (f16*)alloc((size_t)FOUT * NN * 2);      // 4 MB
  f16* wth = (f16*)alloc((size_t)FOUT * FIN * 2);
  f16* wtl = (f16*)alloc((size_t)FOUT * FIN * 2);
  float* wh1 = (float*)alloc((size_t)NN * 4);
  float* wh2 = (float*)alloc((size_t)NN * 4);
  float* m2 = (float*)alloc(256);
  float* zP = (float*)alloc((size_t)JS * NN * 4);

  k_prep_w<<<FIN * FOUT / 256, 256, 0, stream>>>(W, wth, wtl);
  k_gemm1<<<NN / 32, 256, 0, stream>>>(h, wth, wtl, a, whT16, wh1, wh2);
  k_max2<<<1, 256, 0, stream>>>(wh2, m2);
  k_attn<<<(NN / 128) * JS, 256, 0, stream>>>(adj, whT16, wh1, wh2, m2, accP, zP);
  k_combine<<<NN * FOUT / 1024, 256, 0, stream>>>(accP, zP, (float*)d_out);
}